// Round 4
// baseline (218.275 us; speedup 1.0000x reference)
//
#include <hip/hip_runtime.h>

#define BIG 3.0e38f

typedef float vf4 __attribute__((ext_vector_type(4)));

// ---------------------------------------------------------------------------
// Branchless top-3 insert (strict < keeps lowest index on ties, matching
// top_k). Straight-line: 3 v_cmp + 10 v_cndmask, keeps the scan loop a single
// basic block so the compiler can unroll + pipeline the LDS reads.
// ---------------------------------------------------------------------------
__device__ __forceinline__ void insert3(float d, int s,
                                        float& d0, float& d1, float& d2,
                                        int& i0, int& i1, int& i2) {
    const bool b0 = d < d0;
    const bool b1 = d < d1;
    const bool b2 = d < d2;
    d2 = b1 ? d1 : (b2 ? d : d2);   // reads old d1/i1
    i2 = b1 ? i1 : (b2 ? s : i2);
    d1 = b0 ? d0 : (b1 ? d : d1);   // reads old d0/i0
    i1 = b0 ? i0 : (b1 ? s : i1);
    d0 = b0 ? d : d0;
    i0 = b0 ? s : i0;
}

// ---------------------------------------------------------------------------
// Single-pass KNN tile: 256 threads = 32 queries x 8 candidate-splits.
// All S candidates staged once in LDS (float4: x,y,z,|p|^2). Each thread
// scans S/8 candidates; 8 split top-3 lists merged in LDS in ascending split
// order (tie order == full ascending scan). Writes idx/w directly.
// ---------------------------------------------------------------------------
template <int S>
__device__ void knn_tile(const float* __restrict__ xyzF, const float* __restrict__ xyzC,
                         int N, int b, int nb,
                         int* __restrict__ idx, float* __restrict__ w,
                         void* smem) {
    constexpr int SPC = S / 8;
    float4* sc  = (float4*)smem;                       // S * 16 B
    float*  smd = (float*)((char*)smem + S * 16);      // [256][3] floats
    int*    smi = (int*)((char*)smem + S * 16 + 3072); // [256][3] ints
    const int tid = threadIdx.x;

    for (int i = tid; i < S; i += 256) {
        const float x = xyzC[(b * S + i) * 3 + 0];
        const float y = xyzC[(b * S + i) * 3 + 1];
        const float z = xyzC[(b * S + i) * 3 + 2];
        sc[i] = make_float4(x, y, z, x * x + y * y + z * z);
    }
    __syncthreads();

    const int q  = tid & 31;          // query within tile
    const int sp = tid >> 5;          // candidate split 0..7
    const int n  = nb + q;
    const float ax = xyzF[(b * N + n) * 3 + 0];
    const float ay = xyzF[(b * N + n) * 3 + 1];
    const float az = xyzF[(b * N + n) * 3 + 2];
    const float an = ax * ax + ay * ay + az * az;

    float d0 = BIG, d1 = BIG, d2 = BIG;
    int i0 = 0, i1 = 0, i2 = 0;
    const int s0 = sp * SPC;
#pragma unroll 8
    for (int s = s0; s < s0 + SPC; ++s) {
        const float4 p = sc[s];       // 2 distinct addrs per wave -> ~free
        const float t = ax * p.x + ay * p.y + az * p.z;
        const float d = an + p.w - 2.0f * t;   // matches ref formula exactly
        insert3(d, s, d0, d1, d2, i0, i1, i2);
    }

    smd[tid * 3 + 0] = d0; smi[tid * 3 + 0] = i0;   // stride 3 -> <=2-way, free
    smd[tid * 3 + 1] = d1; smi[tid * 3 + 1] = i1;
    smd[tid * 3 + 2] = d2; smi[tid * 3 + 2] = i2;
    __syncthreads();

    if (tid < 32) {                   // one thread per query merges 8 splits
        float e0 = BIG, e1 = BIG, e2 = BIG;
        int j0 = 0, j1 = 0, j2 = 0;
#pragma unroll
        for (int ch = 0; ch < 8; ++ch) {
#pragma unroll
            for (int k = 0; k < 3; ++k) {
                insert3(smd[(ch * 32 + tid) * 3 + k], smi[(ch * 32 + tid) * 3 + k],
                        e0, e1, e2, j0, j1, j2);
            }
        }
        const float r0 = 1.0f / (e0 + 1e-8f);
        const float r1 = 1.0f / (e1 + 1e-8f);
        const float r2 = 1.0f / (e2 + 1e-8f);
        const float rs = r0 + r1 + r2;
        const int nn = nb + tid;
        idx[(b * 3 + 0) * N + nn] = j0;
        idx[(b * 3 + 1) * N + nn] = j1;
        idx[(b * 3 + 2) * N + nn] = j2;
        w[(b * 3 + 0) * N + nn] = r0 / rs;
        w[(b * 3 + 1) * N + nn] = r1 / rs;
        w[(b * 3 + 2) * N + nn] = r2 / rs;
    }
}

// ---------------------------------------------------------------------------
// 64x64 tile transpose [B,C,N] -> point-major out[b][n][c] (row stride OS).
// ---------------------------------------------------------------------------
__device__ void transpose_tile(const float* __restrict__ in, float* __restrict__ out,
                               int C, int N, int OS,
                               int b, int nb, int cb, void* smem) {
    float (*s)[65] = (float (*)[65])smem;
    const int lo = threadIdx.x & 63;
    const int r  = threadIdx.x >> 6;
#pragma unroll
    for (int i = 0; i < 16; ++i) {
        const int cl = r + 4 * i;
        s[cl][lo] = in[((size_t)b * C + cb + cl) * N + nb + lo];
    }
    __syncthreads();
#pragma unroll
    for (int i = 0; i < 16; ++i) {
        const int pl = r + 4 * i;
        out[((size_t)b * N + nb + pl) * OS + cb + lo] = s[lo][pl];
    }
}

// ---------------------------------------------------------------------------
// K1: all mutually-independent prep work. Block types INTERLEAVED (4 knn2 :
// 5 memory per 9 ids) so VALU-bound knn2 co-resides with BW-bound transposes
// on every CU instead of serializing behind them (LDS caps 4 blocks/CU).
//   knn2 : 1024 blocks   knn1: 256   t_x2: 256   t_x1: 512   copy_x0: 256
// ---------------------------------------------------------------------------
__global__ __launch_bounds__(256) void k1_stage(const float* __restrict__ xyz0,
                                                const float* __restrict__ xyz1,
                                                const float* __restrict__ xyz2,
                                                const float* __restrict__ x0,
                                                const float* __restrict__ x1,
                                                const float* __restrict__ x2,
                                                float* __restrict__ x1P,
                                                float* __restrict__ x2P,
                                                int* __restrict__ idx1,
                                                float* __restrict__ w1,
                                                int* __restrict__ idx2,
                                                float* __restrict__ w2,
                                                float* __restrict__ out) {
    __shared__ float4 smem4[2432];   // 38,912 B union: knn2 38,912 / transpose 16,640
    const int id = blockIdx.x;       // 0..2303 = 256 groups of 9
    const int g  = id / 9;
    const int r9 = id - g * 9;
    if (r9 < 4) {
        // ---- knn2: xyz0 vs xyz1 -> idx2/w2 (32 q/blk) ----
        const int kid = g * 4 + r9;          // 0..1023
        const int b  = kid >> 8;
        const int nb = (kid & 255) * 32;
        knn_tile<2048>(xyz0, xyz1, 8192, b, nb, idx2, w2, smem4);
    } else {
        const int mid = g * 5 + (r9 - 4);    // 0..1279
        if (mid < 256) {
            // ---- knn1: xyz1 vs xyz2 -> idx1/w1 ----
            const int b  = mid >> 6;
            const int nb = (mid & 63) * 32;
            knn_tile<512>(xyz1, xyz2, 2048, b, nb, idx1, w1, smem4);
        } else if (mid < 512) {
            // ---- t_x2: x2 -> x2P [B][512][512] ----
            const int r  = mid - 256;
            const int b  = r >> 6;
            const int nb = (r & 7) * 64;
            const int cb = ((r >> 3) & 7) * 64;
            transpose_tile(x2, x2P, 512, 512, 512, b, nb, cb, smem4);
        } else if (mid < 1024) {
            // ---- t_x1: x1 -> x1P [B][2048][256] ----
            const int r  = mid - 512;
            const int b  = r >> 7;
            const int nb = (r & 31) * 64;
            const int cb = ((r >> 5) & 3) * 64;
            transpose_tile(x1, x1P, 256, 2048, 256, b, nb, cb, smem4);
        } else {
            // ---- copy x0 -> out channels 0..127 (NT: pure stream) ----
            const int r  = mid - 1024;       // 0..255
            const int b  = r >> 6;
            const int lb = r & 63;
            const vf4* src = (const vf4*)x0;
            vf4* dst = (vf4*)out;
#pragma unroll
            for (int t = 0; t < 16; ++t) {
                const int i = lb * 4096 + t * 256 + threadIdx.x;   // 0..262143
                const vf4 v = __builtin_nontemporal_load(&src[(size_t)b * (128 * 2048) + i]);
                __builtin_nontemporal_store(v, &dst[(size_t)b * (896 * 2048) + i]);
            }
        }
    }
}

// ---------------------------------------------------------------------------
// K2: final output via composed interpolation, batch pinned to an XCD pair:
// xcd = id&7, b = xcd>>1 -> per-XCD gather working set = x1P(2MB)+x2P(1MB)
// = 3MB < 4MB L2. Consecutive locals walk the 12 c-tiles of one n-tile so
// its 9 gather rows stay hot. Output stores are non-temporal so the 100MB
// write stream doesn't evict the gather tables.
//   ctile 0..3 : out[128+cb+c][n] = 3-gather of x1P with w2
//   ctile 4..11: out[384+cb'+c][n] = 9-gather of x2P with composed weights
// ---------------------------------------------------------------------------
__global__ __launch_bounds__(256) void final_fused(const float* __restrict__ x1P,
                                                   const float* __restrict__ x2P,
                                                   const int* __restrict__ idx1,
                                                   const float* __restrict__ w1,
                                                   const int* __restrict__ idx2,
                                                   const float* __restrict__ w2,
                                                   float* __restrict__ out) {
    __shared__ float tile[64][65];
    __shared__ int   sj[9][64];
    __shared__ float sw[9][64];
    const int id  = blockIdx.x;               // 0..6143
    const int xcd = id & 7;
    const int b   = xcd >> 1;                 // batch pinned to XCD pair
    const int local = ((id >> 3) << 1) | (xcd & 1);   // 0..1535 within batch
    const int ntile = local / 12;             // 0..127
    const int ctile = local - ntile * 12;     // 0..11
    const int nb  = ntile * 64;
    const int tid = threadIdx.x;

    if (ctile < 4) {
        // ------- channels 128..383: 3-gather of x1P with w2 -------
        if (tid < 192) {
            const int p = tid & 63, k = tid >> 6;
            sj[k][p] = idx2[(b * 3 + k) * 8192 + nb + p];
            sw[k][p] = w2[(b * 3 + k) * 8192 + nb + p];
        }
        __syncthreads();
        const int cb = ctile * 64;
        {
            const int c = tid & 63, r = tid >> 6;
            const float* xb = x1P + (size_t)b * 2048 * 256 + cb + c;
#pragma unroll
            for (int i = 0; i < 16; ++i) {
                const int p = r + 4 * i;
                const float v = sw[0][p] * xb[(size_t)sj[0][p] * 256]
                              + sw[1][p] * xb[(size_t)sj[1][p] * 256]
                              + sw[2][p] * xb[(size_t)sj[2][p] * 256];
                tile[p][c] = v;
            }
        }
        __syncthreads();
        {
            const int p = tid & 63, r = tid >> 6;
#pragma unroll
            for (int i = 0; i < 16; ++i) {
                const int cl = r + 4 * i;
                __builtin_nontemporal_store(tile[p][cl],
                    &out[((size_t)b * 896 + 128 + cb + cl) * 8192 + nb + p]);
            }
        }
    } else {
        // ------- channels 384..895: 9-gather of x2P, composed weights -------
        // setup parallelized across 192 threads (3 k-values x 64 points)
        if (tid < 192) {
            const int p = tid & 63, k = tid >> 6;
            const int   j  = idx2[(b * 3 + k) * 8192 + nb + p];
            const float wk = w2[(b * 3 + k) * 8192 + nb + p];
#pragma unroll
            for (int m = 0; m < 3; ++m) {
                sj[k * 3 + m][p] = idx1[(b * 3 + m) * 2048 + j];
                sw[k * 3 + m][p] = wk * w1[(b * 3 + m) * 2048 + j];
            }
        }
        __syncthreads();
        const int cb = (ctile - 4) * 64;   // 0..448 within x2 channel block
        {
            const int c = tid & 63, r = tid >> 6;
            const float* xb = x2P + (size_t)b * 512 * 512 + cb + c;
#pragma unroll
            for (int i = 0; i < 16; ++i) {
                const int p = r + 4 * i;
                float v = 0.0f;
#pragma unroll
                for (int j = 0; j < 9; ++j) {
                    v += sw[j][p] * xb[(size_t)sj[j][p] * 512];
                }
                tile[p][c] = v;
            }
        }
        __syncthreads();
        {
            const int p = tid & 63, r = tid >> 6;
#pragma unroll
            for (int i = 0; i < 16; ++i) {
                const int cl = r + 4 * i;
                __builtin_nontemporal_store(tile[p][cl],
                    &out[((size_t)b * 896 + 384 + cb + cl) * 8192 + nb + p]);
            }
        }
    }
}

extern "C" void kernel_launch(void* const* d_in, const int* in_sizes, int n_in,
                              void* d_out, int out_size, void* d_ws, size_t ws_size,
                              hipStream_t stream) {
    const float* xyz0 = (const float*)d_in[0];  // [4,8192,3]
    const float* xyz1 = (const float*)d_in[1];  // [4,2048,3]
    const float* xyz2 = (const float*)d_in[2];  // [4,512,3]
    const float* x0   = (const float*)d_in[3];  // [4,128,8192]
    const float* x1   = (const float*)d_in[4];  // [4,256,2048]
    const float* x2   = (const float*)d_in[5];  // [4,512,512]
    float* out = (float*)d_out;                 // [4,896,8192]

    // Workspace layout (bytes), total 13,565,952:
    //   x1P   : float[4*2048*256] @ 0          (8,388,608)  point-major x1
    //   x2P   : float[4*512*512]  @ 8,388,608  (4,194,304)  point-major x2
    //   idx1  : int  [4*3*2048]   @ 12,582,912 (98,304)
    //   w1    : float[4*3*2048]   @ 12,681,216 (98,304)
    //   idx2  : int  [4*3*8192]   @ 12,779,520 (393,216)
    //   w2    : float[4*3*8192]   @ 13,172,736 (393,216)
    char* ws = (char*)d_ws;
    float* x1P  = (float*)(ws + 0);
    float* x2P  = (float*)(ws + 8388608);
    int*   idx1 = (int*)(ws + 12582912);
    float* w1   = (float*)(ws + 12681216);
    int*   idx2 = (int*)(ws + 12779520);
    float* w2   = (float*)(ws + 13172736);

    // K1: both KNNs + both point-major transposes + x0 copy, interleaved.
    k1_stage<<<dim3(2304), 256, 0, stream>>>(xyz0, xyz1, xyz2, x0, x1, x2,
                                             x1P, x2P, idx1, w1, idx2, w2, out);
    // K2: composed final interpolation, batch->XCD-pair pinned, NT stores.
    final_fused<<<dim3(6144), 256, 0, stream>>>(x1P, x2P, idx1, w1, idx2, w2, out);
}